// Round 1
// baseline (7846.598 us; speedup 1.0000x reference)
//
#include <hip/hip_runtime.h>
#include <math.h>

// Paraphraser seq2seq: bi-LSTM encoder + attention decoder + fused vocab log-softmax.
// Shapes: S=40, B=32, T=40, E=256, H=512, V=50000. All fp32.

#define S_LEN 40
#define BATCH 32
#define EMB   256
#define HID   512
#define G4H   2048          // 4*H
#define NVOC  50000
#define NDEC  39            // T-1 decoder steps
#define NCHUNK 196          // ceil(50000/256)
#define MROWS 1248          // NDEC*BATCH real rows into vocab GEMM
#define MPAD  1280          // padded to 20*64 row tiles

__device__ __forceinline__ float sigf(float x) { return 1.f / (1.f + expf(-x)); }

// ---------------- zero helper ----------------
__global__ __launch_bounds__(256) void k_zero(float* __restrict__ p, int n) {
  int i = blockIdx.x * 256 + threadIdx.x;
  if (i < n) p[i] = 0.f;
}

// ---------------- embedding gather ----------------
// blocks [0,1280): src_e rows (s*B+b). blocks [1280,2528): tgt_e rows (t*B+b), t<39.
__global__ __launch_bounds__(256) void k_embed(
    const int* __restrict__ src_ids, const int* __restrict__ tgt_ids,
    const float* __restrict__ src_emb, const float* __restrict__ tgt_emb,
    float* __restrict__ src_e, float* __restrict__ tgt_e)
{
  int row = blockIdx.x, tid = threadIdx.x;
  if (row < S_LEN*BATCH) {
    int id = src_ids[row];
    src_e[(size_t)row*EMB + tid] = src_emb[(size_t)id*EMB + tid];
  } else {
    int r = row - S_LEN*BATCH;
    int id = tgt_ids[r];
    tgt_e[(size_t)r*EMB + tid] = tgt_emb[(size_t)id*EMB + tid];
  }
}

// ---------------- generic GEMM: C = A @ W^T (+bias) ----------------
// A: M x K (lda=K), W: N x ldw (row n is the n-th output's weights, first K cols used).
// BM=32, BN=256, BK=16, 256 threads, micro-tile 4 rows x 8 cols.
// rev!=0: A-row remap for the reversed-sequence encoder projection:
//         tile bmi reads A rows (S-1-bmi)*32 + local. Requires gridDim.y==40.
__global__ __launch_bounds__(256) void k_gemm(
    const float* __restrict__ A, const float* __restrict__ W,
    const float* __restrict__ bias, float* __restrict__ C,
    int N, int K, int ldw, int rev)
{
  __shared__ float As[16][36];
  __shared__ float Ws[16][256];
  const int tid = threadIdx.x;
  const int tx = tid & 31, ty = tid >> 5;
  const int bn = (int)blockIdx.x << 8;
  const int bmi = (int)blockIdx.y;
  const int bm = bmi << 5;
  const int arow0 = rev ? ((S_LEN - 1 - bmi) << 5) : bm;

  float acc[4][8];
#pragma unroll
  for (int i = 0; i < 4; i++)
#pragma unroll
    for (int j = 0; j < 8; j++) acc[i][j] = 0.f;

  const int ml = tid >> 3, kl = (tid & 7) << 1;
  const float* aptr = A + (size_t)(arow0 + ml)*K + kl;
  const float* wptr = W + (size_t)(bn + tid)*ldw;

  for (int k0 = 0; k0 < K; k0 += 16) {
    const float2 av  = *(const float2*)(aptr + k0);
    const float4 w0v = *(const float4*)(wptr + k0);
    const float4 w1v = *(const float4*)(wptr + k0 + 4);
    const float4 w2v = *(const float4*)(wptr + k0 + 8);
    const float4 w3v = *(const float4*)(wptr + k0 + 12);
    __syncthreads();
    As[kl][ml]   = av.x;
    As[kl+1][ml] = av.y;
    const float wt[16] = {w0v.x,w0v.y,w0v.z,w0v.w, w1v.x,w1v.y,w1v.z,w1v.w,
                          w2v.x,w2v.y,w2v.z,w2v.w, w3v.x,w3v.y,w3v.z,w3v.w};
#pragma unroll
    for (int kk = 0; kk < 16; kk++) Ws[kk][tid] = wt[kk];
    __syncthreads();
#pragma unroll
    for (int kk = 0; kk < 16; kk++) {
      const float4 a4 = *(const float4*)&As[kk][ty << 2];
      const float4 b0 = *(const float4*)&Ws[kk][tx << 2];
      const float4 b1 = *(const float4*)&Ws[kk][128 + (tx << 2)];
      const float ar[4] = {a4.x, a4.y, a4.z, a4.w};
      const float br[8] = {b0.x, b0.y, b0.z, b0.w, b1.x, b1.y, b1.z, b1.w};
#pragma unroll
      for (int i = 0; i < 4; i++)
#pragma unroll
        for (int j = 0; j < 8; j++) acc[i][j] += ar[i]*br[j];
    }
  }
  float4 bb0 = {0,0,0,0}, bb1 = {0,0,0,0};
  if (bias) {
    bb0 = *(const float4*)&bias[bn + (tx << 2)];
    bb1 = *(const float4*)&bias[bn + 128 + (tx << 2)];
  }
#pragma unroll
  for (int i = 0; i < 4; i++) {
    const int row = bm + (ty << 2) + i;
    float4 o0 = {acc[i][0]+bb0.x, acc[i][1]+bb0.y, acc[i][2]+bb0.z, acc[i][3]+bb0.w};
    float4 o1 = {acc[i][4]+bb1.x, acc[i][5]+bb1.y, acc[i][6]+bb1.z, acc[i][7]+bb1.w};
    *(float4*)&C[(size_t)row*N + bn + (tx << 2)] = o0;
    *(float4*)&C[(size_t)row*N + bn + 128 + (tx << 2)] = o1;
  }
}

// ---------------- encoder recurrent step (both directions in one grid) ----------------
// grid 128: blocks [0,64) forward, [64,128) backward; each owns 8 hidden units (x4 gates, x32 rows).
// gates = xproj[t] + h_{t-1} @ Whh^T; LSTM cell; h,c written to per-step history (race-free).
__global__ __launch_bounds__(256) void k_enc_step(
    int t,
    const float* __restrict__ xproj_f, const float* __restrict__ xproj_b,
    const float* __restrict__ Whh_f, const float* __restrict__ Whh_b,
    float* __restrict__ hs_f, float* __restrict__ hs_b,
    float* __restrict__ cs_f, float* __restrict__ cs_b)
{
  __shared__ float hb[BATCH*HID];   // 64 KB, pair-swizzled [k][r]
  const int dir = (int)blockIdx.x >> 6;
  const int j0 = ((int)blockIdx.x & 63) << 3;
  const float* xproj = dir ? xproj_b : xproj_f;
  const float* Whh   = dir ? Whh_b   : Whh_f;
  float* hs = dir ? hs_b : hs_f;
  float* cs = dir ? cs_b : cs_f;
  const int tid = threadIdx.x;

  if (t > 0) {
    const float* hprev = hs + (size_t)(t-1)*BATCH*HID;
#pragma unroll
    for (int i = 0; i < 64; i++) {
      const int idx = tid + (i << 8);
      const int r = idx >> 9, k = idx & 511;
      const int p = k >> 1;
      hb[((p*32 + ((r + p) & 31)) << 1) + (k & 1)] = hprev[idx];
    }
  }
  __syncthreads();

  const int r = tid & 31, u = tid >> 5;
  const int j = j0 + u;
  const float* xrow = xproj + (size_t)(t*BATCH + r)*G4H;
  float acc[4] = { xrow[j], xrow[HID + j], xrow[2*HID + j], xrow[3*HID + j] };

  if (t > 0) {
    const float* wp[4] = { Whh + (size_t)j*HID,           Whh + (size_t)(HID + j)*HID,
                           Whh + (size_t)(2*HID + j)*HID, Whh + (size_t)(3*HID + j)*HID };
    for (int p = 0; p < 256; p += 4) {
      float hv[8];
#pragma unroll
      for (int q = 0; q < 4; q++) {
        const float2 h2 = *(const float2*)&hb[((p+q)*32 + ((r + p + q) & 31)) << 1];
        hv[2*q] = h2.x; hv[2*q+1] = h2.y;
      }
      const int kb = p << 1;
#pragma unroll
      for (int g = 0; g < 4; g++) {
        const float4 x0 = *(const float4*)(wp[g] + kb);
        const float4 x1 = *(const float4*)(wp[g] + kb + 4);
        acc[g] += hv[0]*x0.x + hv[1]*x0.y + hv[2]*x0.z + hv[3]*x0.w
                + hv[4]*x1.x + hv[5]*x1.y + hv[6]*x1.z + hv[7]*x1.w;
      }
    }
  }
  const float cprev = (t > 0) ? cs[(size_t)(t-1)*BATCH*HID + r*HID + j] : 0.f;
  const float ig = sigf(acc[0]);
  const float fg = sigf(acc[1]);
  const float gg = tanhf(acc[2]);
  const float og = sigf(acc[3]);
  const float cn = fg*cprev + ig*gg;
  const float hn = og*tanhf(cn);
  hs[(size_t)t*BATCH*HID + r*HID + j] = hn;
  cs[(size_t)t*BATCH*HID + r*HID + j] = cn;
}

// ---------------- build enc_hidden (B,S,2H), hT/cT concats ----------------
__global__ __launch_bounds__(256) void k_concat(
    const float* __restrict__ hs_f, const float* __restrict__ hs_b,
    const float* __restrict__ cs_f, const float* __restrict__ cs_b,
    float* __restrict__ enc_hid, float* __restrict__ hcat, float* __restrict__ ccat)
{
  const int blk = blockIdx.x, tid = threadIdx.x;
  if (blk < BATCH*S_LEN) {
    const int b = blk / S_LEN, s = blk - b*S_LEN;
#pragma unroll
    for (int q = 0; q < 4; q++) {
      const int d = tid + (q << 8);
      const float v = (d < HID)
        ? hs_f[(size_t)s*BATCH*HID + b*HID + d]
        : hs_b[(size_t)(S_LEN-1-s)*BATCH*HID + b*HID + (d - HID)];  // hs_b reversed back
      enc_hid[(size_t)blk*(2*HID) + d] = v;
    }
  } else {
    const int rr = blk - BATCH*S_LEN;     // 0..63
    const float* Af = (rr < 32) ? hs_f : cs_f;
    const float* Ab = (rr < 32) ? hs_b : cs_b;
    float* dst = (rr < 32) ? hcat : ccat;
    const int b2 = rr & 31;
#pragma unroll
    for (int q = 0; q < 4; q++) {
      const int d = tid + (q << 8);
      const float v = (d < HID)
        ? Af[(size_t)(S_LEN-1)*BATCH*HID + b2*HID + d]
        : Ab[(size_t)(S_LEN-1)*BATCH*HID + b2*HID + (d - HID)];
      dst[(size_t)b2*(2*HID) + d] = v;
    }
  }
}

// ---------------- decoder LSTM step ----------------
// gates = dec_xproj[t] (emb part + bias, precomputed) + [o_prev|h] @ [Wih[:,256:] | Whh]^T
// grid 64 blocks x 8 hidden units. Reads slot t of dec_hs/dec_cs/outs, writes slot t+1.
__global__ __launch_bounds__(256) void k_dec_step(
    int t,
    const float* __restrict__ dec_xp,
    const float* __restrict__ Wih, const float* __restrict__ Whh,
    float* __restrict__ dec_hs, float* __restrict__ dec_cs,
    const float* __restrict__ outs)
{
  __shared__ float xb[BATCH*1024];   // 128 KB: [o_prev(512) | h(512)] pair-swizzled
  const int j0 = (int)blockIdx.x << 3;
  const int tid = threadIdx.x;
  const float* oprev = outs   + (size_t)t*BATCH*HID;
  const float* hprev = dec_hs + (size_t)t*BATCH*HID;
#pragma unroll
  for (int i = 0; i < 128; i++) {
    const int idx = tid + (i << 8);
    const int r = idx >> 10, k = idx & 1023;
    const float v = (k < HID) ? oprev[r*HID + k] : hprev[r*HID + (k - HID)];
    const int p = k >> 1;
    xb[((p*32 + ((r + p) & 31)) << 1) + (k & 1)] = v;
  }
  __syncthreads();
  const int r = tid & 31, u = tid >> 5;
  const int j = j0 + u;
  const float* xrow = dec_xp + (size_t)(t*BATCH + r)*G4H;
  float acc[4] = { xrow[j], xrow[HID + j], xrow[2*HID + j], xrow[3*HID + j] };
  {
    // segment 1: k 0..511 = o_prev, weights Wih cols 256..767
    const float* wp[4] = { Wih + (size_t)j*768 + 256,           Wih + (size_t)(HID + j)*768 + 256,
                           Wih + (size_t)(2*HID + j)*768 + 256, Wih + (size_t)(3*HID + j)*768 + 256 };
    for (int p = 0; p < 256; p += 4) {
      float hv[8];
#pragma unroll
      for (int q = 0; q < 4; q++) {
        const float2 h2 = *(const float2*)&xb[((p+q)*32 + ((r + p + q) & 31)) << 1];
        hv[2*q] = h2.x; hv[2*q+1] = h2.y;
      }
      const int kb = p << 1;
#pragma unroll
      for (int g = 0; g < 4; g++) {
        const float4 x0 = *(const float4*)(wp[g] + kb);
        const float4 x1 = *(const float4*)(wp[g] + kb + 4);
        acc[g] += hv[0]*x0.x + hv[1]*x0.y + hv[2]*x0.z + hv[3]*x0.w
                + hv[4]*x1.x + hv[5]*x1.y + hv[6]*x1.z + hv[7]*x1.w;
      }
    }
  }
  {
    // segment 2: k 512..1023 = h, weights Whh
    const float* wp[4] = { Whh + (size_t)j*HID,           Whh + (size_t)(HID + j)*HID,
                           Whh + (size_t)(2*HID + j)*HID, Whh + (size_t)(3*HID + j)*HID };
    for (int p = 256; p < 512; p += 4) {
      float hv[8];
#pragma unroll
      for (int q = 0; q < 4; q++) {
        const float2 h2 = *(const float2*)&xb[((p+q)*32 + ((r + p + q) & 31)) << 1];
        hv[2*q] = h2.x; hv[2*q+1] = h2.y;
      }
      const int kb = (p - 256) << 1;
#pragma unroll
      for (int g = 0; g < 4; g++) {
        const float4 x0 = *(const float4*)(wp[g] + kb);
        const float4 x1 = *(const float4*)(wp[g] + kb + 4);
        acc[g] += hv[0]*x0.x + hv[1]*x0.y + hv[2]*x0.z + hv[3]*x0.w
                + hv[4]*x1.x + hv[5]*x1.y + hv[6]*x1.z + hv[7]*x1.w;
      }
    }
  }
  const float cprev = dec_cs[(size_t)t*BATCH*HID + r*HID + j];
  const float ig = sigf(acc[0]);
  const float fg = sigf(acc[1]);
  const float gg = tanhf(acc[2]);
  const float og = sigf(acc[3]);
  const float cn = fg*cprev + ig*gg;
  const float hn = og*tanhf(cn);
  dec_hs[(size_t)(t+1)*BATCH*HID + r*HID + j] = hn;
  dec_cs[(size_t)(t+1)*BATCH*HID + r*HID + j] = cn;
}

// ---------------- attention + combine (one block per batch element) ----------------
__global__ __launch_bounds__(256) void k_attn(
    int t,
    const float* __restrict__ dec_hs, const float* __restrict__ enc_proj,
    const float* __restrict__ enc_hid, const float* __restrict__ enc_masks,
    const float* __restrict__ W_comb, float* __restrict__ outs)
{
  __shared__ float hl[HID];
  __shared__ float ctx[2*HID];
  __shared__ float sc[S_LEN];
  const int b = (int)blockIdx.x, tid = threadIdx.x;
  const float* h = dec_hs + (size_t)(t+1)*BATCH*HID + (size_t)b*HID;
  hl[tid] = h[tid];
  hl[tid + 256] = h[tid + 256];
  __syncthreads();
  // scores[s] = enc_proj[b,s,:] . h   (wave w handles s = w, w+4, ...)
  const int w = tid >> 6, lane = tid & 63;
  for (int si = w; si < S_LEN; si += 4) {
    const float* ep = enc_proj + ((size_t)b*S_LEN + si)*HID;
    float partial = 0.f;
#pragma unroll
    for (int k = 0; k < 8; k++) partial += ep[lane + (k << 6)]*hl[lane + (k << 6)];
#pragma unroll
    for (int m = 32; m >= 1; m >>= 1) partial += __shfl_xor(partial, m, 64);
    if (lane == 0) sc[si] = (enc_masks[b*S_LEN + si] > 0.f) ? -INFINITY : partial;
  }
  __syncthreads();
  // softmax over 40 (redundant per-thread reads are LDS broadcasts)
  float mx = -INFINITY;
  for (int s2 = 0; s2 < S_LEN; s2++) mx = fmaxf(mx, sc[s2]);
  float sm = 0.f;
  for (int s2 = 0; s2 < S_LEN; s2++) sm += expf(sc[s2] - mx);
  const float inv = 1.f/sm;
  const float myatt = (tid < S_LEN) ? expf(sc[tid] - mx)*inv : 0.f;
  __syncthreads();
  if (tid < S_LEN) sc[tid] = myatt;
  __syncthreads();
  // ctx = att . enc_hidden[b]
#pragma unroll
  for (int q = 0; q < 4; q++) {
    const int d = tid + (q << 8);
    float s2 = 0.f;
    for (int si = 0; si < S_LEN; si++) s2 += sc[si]*enc_hid[((size_t)b*S_LEN + si)*(2*HID) + d];
    ctx[d] = s2;
  }
  __syncthreads();
  // o_t = tanh([h|ctx] @ W_comb^T)
#pragma unroll
  for (int q = 0; q < 2; q++) {
    const int jj = tid + (q << 8);
    const float* wr = W_comb + (size_t)jj*1536;
    float a = 0.f;
    for (int k = 0; k < HID; k += 4) {
      const float4 w4 = *(const float4*)(wr + k);
      a += w4.x*hl[k] + w4.y*hl[k+1] + w4.z*hl[k+2] + w4.w*hl[k+3];
    }
    for (int k = 0; k < 2*HID; k += 4) {
      const float4 w4 = *(const float4*)(wr + HID + k);
      a += w4.x*ctx[k] + w4.y*ctx[k+1] + w4.z*ctx[k+2] + w4.w*ctx[k+3];
    }
    outs[(size_t)(t+1)*BATCH*HID + (size_t)b*HID + jj] = tanhf(a);
  }
}

// ---------------- vocab GEMM with fused online log-softmax partials ----------------
// A: MPAD x 512 (outs rows, padded tail rows are zeros). W: 50000 x 512.
// BM=64, BN=256, BK=16, micro 8x8. Per (row, 256-col chunk): writes chunk max and
// sum(exp(logit-max)); the chunk containing tgt[row] also writes picked[row].
__global__ __launch_bounds__(256) void k_vocab(
    const float* __restrict__ A, const float* __restrict__ W,
    const int* __restrict__ ptgt,
    float* __restrict__ pmax, float* __restrict__ psum, float* __restrict__ picked)
{
  __shared__ float As[16][68];
  __shared__ float Ws[16][256];
  const int tid = threadIdx.x;
  const int tx = tid & 31, ty = tid >> 5;
  const int bn = (int)blockIdx.x << 8;
  const int bm = (int)blockIdx.y << 6;

  float acc[8][8];
#pragma unroll
  for (int i = 0; i < 8; i++)
#pragma unroll
    for (int j = 0; j < 8; j++) acc[i][j] = 0.f;

  const int ml = tid >> 2, kl = (tid & 3) << 2;
  const float* aptr = A + (size_t)(bm + ml)*HID + kl;
  int wrow = bn + tid; if (wrow >= NVOC) wrow = NVOC - 1;   // clamp; masked in epilogue
  const float* wptr = W + (size_t)wrow*HID;

  for (int k0 = 0; k0 < HID; k0 += 16) {
    const float4 av  = *(const float4*)(aptr + k0);
    const float4 w0v = *(const float4*)(wptr + k0);
    const float4 w1v = *(const float4*)(wptr + k0 + 4);
    const float4 w2v = *(const float4*)(wptr + k0 + 8);
    const float4 w3v = *(const float4*)(wptr + k0 + 12);
    __syncthreads();
    As[kl][ml] = av.x; As[kl+1][ml] = av.y; As[kl+2][ml] = av.z; As[kl+3][ml] = av.w;
    const float wt[16] = {w0v.x,w0v.y,w0v.z,w0v.w, w1v.x,w1v.y,w1v.z,w1v.w,
                          w2v.x,w2v.y,w2v.z,w2v.w, w3v.x,w3v.y,w3v.z,w3v.w};
#pragma unroll
    for (int kk = 0; kk < 16; kk++) Ws[kk][tid] = wt[kk];
    __syncthreads();
#pragma unroll
    for (int kk = 0; kk < 16; kk++) {
      const float4 a0 = *(const float4*)&As[kk][ty << 3];
      const float4 a1 = *(const float4*)&As[kk][(ty << 3) + 4];
      const float4 b0 = *(const float4*)&Ws[kk][tx << 2];
      const float4 b1 = *(const float4*)&Ws[kk][128 + (tx << 2)];
      const float ar[8] = {a0.x,a0.y,a0.z,a0.w, a1.x,a1.y,a1.z,a1.w};
      const float br[8] = {b0.x,b0.y,b0.z,b0.w, b1.x,b1.y,b1.z,b1.w};
#pragma unroll
      for (int i = 0; i < 8; i++)
#pragma unroll
        for (int j = 0; j < 8; j++) acc[i][j] += ar[i]*br[j];
    }
  }
  // epilogue: per-row online max / sum-exp over this 256-col chunk (width-32 shuffles)
#pragma unroll
  for (int i = 0; i < 8; i++) {
    const int row = bm + (ty << 3) + i;
    float mx = -INFINITY;
#pragma unroll
    for (int j = 0; j < 8; j++) {
      const int col = bn + ((j < 4) ? (tx << 2) + j : 128 + (tx << 2) + j - 4);
      if (col < NVOC) mx = fmaxf(mx, acc[i][j]);
    }
#pragma unroll
    for (int m = 16; m >= 1; m >>= 1) mx = fmaxf(mx, __shfl_xor(mx, m, 32));
    float sm = 0.f;
#pragma unroll
    for (int j = 0; j < 8; j++) {
      const int col = bn + ((j < 4) ? (tx << 2) + j : 128 + (tx << 2) + j - 4);
      if (col < NVOC) sm += expf(acc[i][j] - mx);
    }
#pragma unroll
    for (int m = 16; m >= 1; m >>= 1) sm += __shfl_xor(sm, m, 32);
    if (tx == 0) {
      pmax[(size_t)row*NCHUNK + blockIdx.x] = mx;
      psum[(size_t)row*NCHUNK + blockIdx.x] = sm;
    }
    if (row < MROWS) {
      const int tt = row >> 5, bb = row & 31;
      const int tv = ptgt[(tt + 1)*BATCH + bb];
      const int rel = tv - bn;
      if (rel >= 0 && rel < 256) {
#pragma unroll
        for (int j = 0; j < 8; j++) {
          const int cl = (j < 4) ? (tx << 2) + j : 128 + (tx << 2) + j - 4;
          if (cl == rel) picked[row] = acc[i][j];
        }
      }
    }
  }
}

// ---------------- final reduce: per b, sum over t of (picked - lse) * (tgt != 0) ----------------
__global__ __launch_bounds__(256) void k_final(
    const float* __restrict__ pmax, const float* __restrict__ psum,
    const float* __restrict__ picked, const int* __restrict__ ptgt,
    float* __restrict__ out)
{
  __shared__ float red[8];
  const int b = (int)blockIdx.x, tid = threadIdx.x;
  const int lane = tid & 63, w = tid >> 6;
  float accum = 0.f;
  for (int t = 0; t < NDEC; t++) {
    const int row = t*BATCH + b;
    const float* pm = pmax + (size_t)row*NCHUNK;
    const float* ps = psum + (size_t)row*NCHUNK;
    float mx = -INFINITY;
    for (int c = tid; c < NCHUNK; c += 256) mx = fmaxf(mx, pm[c]);
#pragma unroll
    for (int m = 32; m >= 1; m >>= 1) mx = fmaxf(mx, __shfl_xor(mx, m, 64));
    if (lane == 0) red[w] = mx;
    __syncthreads();
    mx = fmaxf(fmaxf(red[0], red[1]), fmaxf(red[2], red[3]));
    __syncthreads();
    float sm = 0.f;
    for (int c = tid; c < NCHUNK; c += 256) sm += ps[c]*expf(pm[c] - mx);
#pragma unroll
    for (int m = 32; m >= 1; m >>= 1) sm += __shfl_xor(sm, m, 64);
    if (lane == 0) red[w] = sm;
    __syncthreads();
    sm = red[0] + red[1] + red[2] + red[3];
    __syncthreads();
    if (tid == 0) {
      const int tv = ptgt[(t + 1)*BATCH + b];
      if (tv != 0) accum += picked[row] - (mx + logf(sm));
    }
  }
  if (tid == 0) out[b] = accum;
}

// ---------------- host ----------------
extern "C" void kernel_launch(void* const* d_in, const int* in_sizes, int n_in,
                              void* d_out, int out_size, void* d_ws, size_t ws_size,
                              hipStream_t stream) {
  (void)in_sizes; (void)n_in; (void)out_size; (void)ws_size;
  const int*   p_src     = (const int*)d_in[0];
  const int*   p_tgt     = (const int*)d_in[1];
  const float* enc_masks = (const float*)d_in[2];
  const float* src_embed = (const float*)d_in[3];
  const float* tgt_embed = (const float*)d_in[4];
  const float* Wih_f = (const float*)d_in[5];
  const float* Whh_f = (const float*)d_in[6];
  const float* b_f   = (const float*)d_in[7];
  const float* Wih_b = (const float*)d_in[8];
  const float* Whh_b = (const float*)d_in[9];
  const float* b_b   = (const float*)d_in[10];
  const float* dWih  = (const float*)d_in[11];
  const float* dWhh  = (const float*)d_in[12];
  const float* db    = (const float*)d_in[13];
  const float* W_h   = (const float*)d_in[14];
  const float* W_c   = (const float*)d_in[15];
  const float* W_att = (const float*)d_in[16];
  const float* W_comb= (const float*)d_in[17];
  const float* W_voc = (const float*)d_in[18];
  float* out = (float*)d_out;

  float* p = (float*)d_ws;
  float* src_e    = p; p += S_LEN*BATCH*EMB;        // 327680
  float* tgt_e    = p; p += NDEC*BATCH*EMB;         // 319488
  float* xproj_f  = p; p += S_LEN*BATCH*G4H;        // 2621440
  float* xproj_b  = p; p += S_LEN*BATCH*G4H;
  float* dec_xp   = p; p += NDEC*BATCH*G4H;         // 2555904
  float* hs_f     = p; p += S_LEN*BATCH*HID;
  float* hs_b     = p; p += S_LEN*BATCH*HID;
  float* cs_f     = p; p += S_LEN*BATCH*HID;
  float* cs_b     = p; p += S_LEN*BATCH*HID;
  float* enc_hid  = p; p += BATCH*S_LEN*2*HID;      // 1310720
  float* enc_proj = p; p += BATCH*S_LEN*HID;
  float* hcat     = p; p += BATCH*2*HID;
  float* ccat     = p; p += BATCH*2*HID;
  float* dec_hs   = p; p += (NDEC+1)*BATCH*HID;     // slot 0 = init
  float* dec_cs   = p; p += (NDEC+1)*BATCH*HID;
  float* outs     = p; p += (NDEC+2)*BATCH*HID;     // slots 0..40: 0 = o_{-1}=0, 40 = vocab pad rows
  float* pmaxb    = p; p += (size_t)MPAD*NCHUNK;
  float* psumb    = p; p += (size_t)MPAD*NCHUNK;
  float* pickedb  = p; p += MPAD;

  // init: outs slot 0 (o_prev at t=0) and slot 40 (vocab row padding) = 0
  k_zero<<<64, 256, 0, stream>>>(outs, BATCH*HID);
  k_zero<<<64, 256, 0, stream>>>(outs + (size_t)(NDEC+1)*BATCH*HID, BATCH*HID);

  // embeddings
  k_embed<<<S_LEN*BATCH + NDEC*BATCH, 256, 0, stream>>>(p_src, p_tgt, src_embed, tgt_embed, src_e, tgt_e);

  // batched input projections (bias folded here)
  k_gemm<<<dim3(8, 40), 256, 0, stream>>>(src_e, Wih_f, b_f, xproj_f, G4H, EMB, EMB, 0);
  k_gemm<<<dim3(8, 40), 256, 0, stream>>>(src_e, Wih_b, b_b, xproj_b, G4H, EMB, EMB, 1);  // reversed rows
  k_gemm<<<dim3(8, NDEC), 256, 0, stream>>>(tgt_e, dWih, db, dec_xp, G4H, EMB, 768, 0);   // emb cols of dec_Wih

  // encoder recurrence, both directions per launch
  for (int t = 0; t < S_LEN; t++)
    k_enc_step<<<128, 256, 0, stream>>>(t, xproj_f, xproj_b, Whh_f, Whh_b, hs_f, hs_b, cs_f, cs_b);

  k_concat<<<BATCH*S_LEN + 64, 256, 0, stream>>>(hs_f, hs_b, cs_f, cs_b, enc_hid, hcat, ccat);

  // enc_proj = enc_hidden @ W_att^T ; decoder init h/c
  k_gemm<<<dim3(2, 40), 256, 0, stream>>>(enc_hid, W_att, nullptr, enc_proj, HID, 2*HID, 2*HID, 0);
  k_gemm<<<dim3(2, 1), 256, 0, stream>>>(hcat, W_h, nullptr, dec_hs, HID, 2*HID, 2*HID, 0);
  k_gemm<<<dim3(2, 1), 256, 0, stream>>>(ccat, W_c, nullptr, dec_cs, HID, 2*HID, 2*HID, 0);

  // decoder
  for (int t = 0; t < NDEC; t++) {
    k_dec_step<<<64, 256, 0, stream>>>(t, dec_xp, dWih, dWhh, dec_hs, dec_cs, outs);
    k_attn<<<32, 256, 0, stream>>>(t, dec_hs, enc_proj, enc_hid, enc_masks, W_comb, outs);
  }

  // vocab projection + fused log-softmax
  k_vocab<<<dim3(NCHUNK, MPAD/64), 256, 0, stream>>>(outs + BATCH*HID, W_voc, p_tgt, pmaxb, psumb, pickedb);
  k_final<<<32, 256, 0, stream>>>(pmaxb, psumb, pickedb, p_tgt, out);
}